// Round 10
// baseline (159.402 us; speedup 1.0000x reference)
//
#include <hip/hip_runtime.h>

// VQ: x [B=64, D=64, H=32, W=32] fp32, E [D=64, K=1024] fp32.
// flat rows N = B*H*W = 65536 over (b, h, w) order.
// d_out (float32): [0,4194304) quantized [B,D,H,W]; [4194304] dict_loss;
//   [4194305] commit_loss; [4194306,+65536) indices as floats.
//
// Round-10: R9 structure, launch_bounds(256,2). R9's VGPR=52 showed the
// (256,4)/128-cap allocator demoting x_r[64] to per-kt reloads; R2/R4 proved
// the (256,2)/256-cap keeps ~100 VGPRs resident. lane = row; x row in 64
// VGPRs (global coalesced loads, static indices only); wave owns 16-k slice;
// E + esq via wave-uniform s_load from L2; main loop: 16 v_fmac per d-step,
// zero LDS, zero barriers. ILP (16 acc chains) covers latency at 2 waves/SIMD.

#define DDIM 64
#define KNUM 1024
#define HWN  1024
#define ROWS_PER_BLOCK 64

typedef __attribute__((ext_vector_type(8))) float float8v;

__global__ __launch_bounds__(256) void vq_esq_kernel(const float* __restrict__ E,
                                                     float* __restrict__ esq) {
    int k = blockIdx.x * 256 + threadIdx.x;  // 4 blocks x 256 = 1024
    float s = 0.f;
    #pragma unroll 8
    for (int d = 0; d < DDIM; ++d) {
        float e = E[d * KNUM + k];
        s = fmaf(e, e, s);
    }
    esq[k] = s;
}

__global__ __launch_bounds__(256, 2) void vq_main_kernel(const float* __restrict__ x,
                                                         const float* __restrict__ E,
                                                         const float* __restrict__ esq,
                                                         float* __restrict__ out_q,
                                                         float* __restrict__ out_idx,
                                                         float* __restrict__ partial) {
    __shared__ float bdls[4 * ROWS_PER_BLOCK];  // per-wave row winners (dist)
    __shared__ int   bkls[4 * ROWS_PER_BLOCK];  // per-wave row winners (k)
    __shared__ int   klds[ROWS_PER_BLOCK];
    __shared__ float redlds[4];

    const int t  = threadIdx.x;
    const int wv = t >> 6;        // wave 0..3
    const int ln = t & 63;        // lane = row
    const int n0 = blockIdx.x * ROWS_PER_BLOCK;
    const int b   = n0 >> 10;
    const int hw0 = n0 & 1023;

    // ---- this lane's x row -> 64 VGPRs (coalesced global dword loads) ----
    const float* xcol = x + (size_t)b * (DDIM * HWN) + hw0 + ln;
    float x_r[DDIM];
    #pragma unroll
    for (int d = 0; d < DDIM; ++d)
        x_r[d] = xcol[d * HWN];

    const int wvu = __builtin_amdgcn_readfirstlane(wv);  // wave-uniform

    float best  = 3.4e38f;
    int   bestk = 0;

    // 16 kt-iters; wave wv covers k = kt*64 + wvu*16 .. +15 each iter.
    for (int kt = 0; kt < 16; ++kt) {
        const int kbase = kt * 64 + wvu * 16;
        const float* ep = E + kbase;

        float s[16];
        #pragma unroll
        for (int m = 0; m < 16; ++m) s[m] = 0.f;

        #pragma unroll
        for (int d = 0; d < DDIM; ++d) {
            float8v e0 = *reinterpret_cast<const float8v*>(ep + d * KNUM);      // uniform
            float8v e1 = *reinterpret_cast<const float8v*>(ep + d * KNUM + 8);  //  -> s_load
            float xv = x_r[d];
            #pragma unroll
            for (int m = 0; m < 8; ++m) {
                s[m]     = fmaf(xv, e0[m], s[m]);
                s[m + 8] = fmaf(xv, e1[m], s[m + 8]);
            }
        }

        float8v q0 = *reinterpret_cast<const float8v*>(esq + kbase);
        float8v q1 = *reinterpret_cast<const float8v*>(esq + kbase + 8);
        #pragma unroll
        for (int m = 0; m < 16; ++m) {
            float eqv  = (m < 8) ? q0[m & 7] : q1[m & 7];
            float dist = fmaf(-2.f, s[m], eqv);   // |e|^2 - 2 x.e (|x|^2 const per row)
            int   k    = kbase + m;
            if (dist < best) { best = dist; bestk = k; }  // kt,m ascending -> first-min
        }
    }

    bdls[wv * 64 + ln] = best;
    bkls[wv * 64 + ln] = bestk;
    __syncthreads();

    // cross-wave merge: thread t<64 owns row t (lexicographic (dist, k) min)
    if (t < ROWS_PER_BLOCK) {
        float bd = bdls[t]; int bk = bkls[t];
        #pragma unroll
        for (int w = 1; w < 4; ++w) {
            float od = bdls[w * 64 + t]; int ok = bkls[w * 64 + t];
            if (od < bd || (od == bd && ok < bk)) { bd = od; bk = ok; }
        }
        klds[t] = bk;
        out_idx[n0 + t] = (float)bk;
    }
    __syncthreads();

    // epilogue: STATIC d-loop; wave-uniform guard picks this wave's 16 d's.
    // x_r accesses are compile-time-indexed -> stays in VGPRs (rule #20).
    const int kwin = klds[ln];
    float lsum = 0.f;
    float* outbase = out_q + (size_t)b * (DDIM * HWN) + hw0 + ln;
    #pragma unroll
    for (int d = 0; d < DDIM; ++d) {
        if ((d >> 4) == wv) {                  // wave-uniform branch
            float q    = E[d * KNUM + kwin];   // L2-resident gather
            float diff = x_r[d] - q;
            lsum = fmaf(diff, diff, lsum);
            outbase[d * HWN] = q;              // coalesced along hw
        }
    }

    #pragma unroll
    for (int off = 32; off >= 1; off >>= 1)
        lsum += __shfl_xor(lsum, off);
    if ((t & 63) == 0) redlds[t >> 6] = lsum;
    __syncthreads();
    if (t == 0)
        partial[blockIdx.x] = (redlds[0] + redlds[1]) + (redlds[2] + redlds[3]);
}

__global__ __launch_bounds__(256) void vq_loss_kernel(const float* __restrict__ partial,
                                                      float* __restrict__ out_loss) {
    __shared__ float red[4];
    int t = threadIdx.x;
    float s = 0.f;
    #pragma unroll
    for (int it = 0; it < 4; ++it) s += partial[it * 256 + t];
    #pragma unroll
    for (int off = 32; off >= 1; off >>= 1) s += __shfl_xor(s, off);
    if ((t & 63) == 0) red[t >> 6] = s;
    __syncthreads();
    if (t == 0) {
        float loss = ((red[0] + red[1]) + (red[2] + red[3])) / 4194304.f;
        out_loss[0] = loss;   // dictionary_loss
        out_loss[1] = loss;   // commitment_loss (numerically identical)
    }
}

extern "C" void kernel_launch(void* const* d_in, const int* in_sizes, int n_in,
                              void* d_out, int out_size, void* d_ws, size_t ws_size,
                              hipStream_t stream) {
    const float* x = (const float*)d_in[0];
    const float* E = (const float*)d_in[1];
    float* out      = (float*)d_out;
    float* out_q    = out;             // 4194304
    float* out_loss = out + 4194304;   // 2 scalars
    float* out_idx  = out + 4194306;   // 65536 indices (as float)
    float* esq      = (float*)d_ws;    // 1024 floats
    float* partial  = esq + 1024;      // 1024 floats

    vq_esq_kernel<<<4, 256, 0, stream>>>(E, esq);
    vq_main_kernel<<<1024, 256, 0, stream>>>(x, E, esq, out_q, out_idx, partial);
    vq_loss_kernel<<<1, 256, 0, stream>>>(partial, out_loss);
}

// Round 11
// 159.117 us; speedup vs baseline: 1.0018x; 1.0018x over previous
//
#include <hip/hip_runtime.h>

// VQ: x [B=64, D=64, H=32, W=32] fp32, E [D=64, K=1024] fp32.
// flat rows N = B*H*W = 65536 over (b, h, w) order.
// d_out (float32): [0,4194304) quantized [B,D,H,W]; [4194304] dict_loss;
//   [4194305] commit_loss; [4194306,+65536) indices as floats.
//
// Round-11: R10 structure + ASM-PINNED x registers. R9/R10 showed LLVM's
// pressure heuristic sinks the 64 x-loads into the kt-loop (VGPR=52, 2.3x
// VALU inflation) regardless of launch-bounds cap. Fix: pass each x_r[d]
// through asm volatile("" : "+v") after the load - as opaque asm outputs
// they cannot be rematerialized by reloading, forcing all 64 to stay
// resident. Main loop: 16 v_fmac (VGPRxSGPR) per d-step, E + esq via
// wave-uniform s_load from L2, ZERO LDS / VMEM / barriers.

#define DDIM 64
#define KNUM 1024
#define HWN  1024
#define ROWS_PER_BLOCK 64

typedef __attribute__((ext_vector_type(8))) float float8v;

__global__ __launch_bounds__(256) void vq_esq_kernel(const float* __restrict__ E,
                                                     float* __restrict__ esq) {
    int k = blockIdx.x * 256 + threadIdx.x;  // 4 blocks x 256 = 1024
    float s = 0.f;
    #pragma unroll 8
    for (int d = 0; d < DDIM; ++d) {
        float e = E[d * KNUM + k];
        s = fmaf(e, e, s);
    }
    esq[k] = s;
}

__global__ __launch_bounds__(256, 2) void vq_main_kernel(const float* __restrict__ x,
                                                         const float* __restrict__ E,
                                                         const float* __restrict__ esq,
                                                         float* __restrict__ out_q,
                                                         float* __restrict__ out_idx,
                                                         float* __restrict__ partial) {
    __shared__ float bdls[4 * ROWS_PER_BLOCK];  // per-wave row winners (dist)
    __shared__ int   bkls[4 * ROWS_PER_BLOCK];  // per-wave row winners (k)
    __shared__ int   klds[ROWS_PER_BLOCK];
    __shared__ float redlds[4];

    const int t  = threadIdx.x;
    const int wv = t >> 6;        // wave 0..3
    const int ln = t & 63;        // lane = row
    const int n0 = blockIdx.x * ROWS_PER_BLOCK;
    const int b   = n0 >> 10;
    const int hw0 = n0 & 1023;

    // ---- this lane's x row -> 64 VGPRs (coalesced global dword loads) ----
    const float* xcol = x + (size_t)b * (DDIM * HWN) + hw0 + ln;
    float x_r[DDIM];
    #pragma unroll
    for (int d = 0; d < DDIM; ++d)
        x_r[d] = xcol[d * HWN];
    // Pin: opaque asm outputs cannot be rematerialized-by-reload, so the
    // allocator must keep all 64 values in VGPRs across the kt-loop.
    #pragma unroll
    for (int d = 0; d < DDIM; ++d)
        asm volatile("" : "+v"(x_r[d]));

    const int wvu = __builtin_amdgcn_readfirstlane(wv);  // wave-uniform

    float best  = 3.4e38f;
    int   bestk = 0;

    // 16 kt-iters; wave wv covers k = kt*64 + wvu*16 .. +15 each iter.
    for (int kt = 0; kt < 16; ++kt) {
        const int kbase = kt * 64 + wvu * 16;
        const float* ep = E + kbase;

        float s[16];
        #pragma unroll
        for (int m = 0; m < 16; ++m) s[m] = 0.f;

        #pragma unroll
        for (int d = 0; d < DDIM; ++d) {
            float8v e0 = *reinterpret_cast<const float8v*>(ep + d * KNUM);      // uniform
            float8v e1 = *reinterpret_cast<const float8v*>(ep + d * KNUM + 8);  //  -> s_load
            float xv = x_r[d];
            #pragma unroll
            for (int m = 0; m < 8; ++m) {
                s[m]     = fmaf(xv, e0[m], s[m]);
                s[m + 8] = fmaf(xv, e1[m], s[m + 8]);
            }
        }

        float8v q0 = *reinterpret_cast<const float8v*>(esq + kbase);
        float8v q1 = *reinterpret_cast<const float8v*>(esq + kbase + 8);
        #pragma unroll
        for (int m = 0; m < 16; ++m) {
            float eqv  = (m < 8) ? q0[m & 7] : q1[m & 7];
            float dist = fmaf(-2.f, s[m], eqv);   // |e|^2 - 2 x.e (|x|^2 const per row)
            int   k    = kbase + m;
            if (dist < best) { best = dist; bestk = k; }  // kt,m ascending -> first-min
        }
    }

    bdls[wv * 64 + ln] = best;
    bkls[wv * 64 + ln] = bestk;
    __syncthreads();

    // cross-wave merge: thread t<64 owns row t (lexicographic (dist, k) min)
    if (t < ROWS_PER_BLOCK) {
        float bd = bdls[t]; int bk = bkls[t];
        #pragma unroll
        for (int w = 1; w < 4; ++w) {
            float od = bdls[w * 64 + t]; int ok = bkls[w * 64 + t];
            if (od < bd || (od == bd && ok < bk)) { bd = od; bk = ok; }
        }
        klds[t] = bk;
        out_idx[n0 + t] = (float)bk;
    }
    __syncthreads();

    // epilogue: STATIC d-loop; wave-uniform guard picks this wave's 16 d's.
    const int kwin = klds[ln];
    float lsum = 0.f;
    float* outbase = out_q + (size_t)b * (DDIM * HWN) + hw0 + ln;
    #pragma unroll
    for (int d = 0; d < DDIM; ++d) {
        if ((d >> 4) == wv) {                  // wave-uniform branch
            float q    = E[d * KNUM + kwin];   // L2-resident gather
            float diff = x_r[d] - q;
            lsum = fmaf(diff, diff, lsum);
            outbase[d * HWN] = q;              // coalesced along hw
        }
    }

    #pragma unroll
    for (int off = 32; off >= 1; off >>= 1)
        lsum += __shfl_xor(lsum, off);
    if ((t & 63) == 0) redlds[t >> 6] = lsum;
    __syncthreads();
    if (t == 0)
        partial[blockIdx.x] = (redlds[0] + redlds[1]) + (redlds[2] + redlds[3]);
}

__global__ __launch_bounds__(256) void vq_loss_kernel(const float* __restrict__ partial,
                                                      float* __restrict__ out_loss) {
    __shared__ float red[4];
    int t = threadIdx.x;
    float s = 0.f;
    #pragma unroll
    for (int it = 0; it < 4; ++it) s += partial[it * 256 + t];
    #pragma unroll
    for (int off = 32; off >= 1; off >>= 1) s += __shfl_xor(s, off);
    if ((t & 63) == 0) red[t >> 6] = s;
    __syncthreads();
    if (t == 0) {
        float loss = ((red[0] + red[1]) + (red[2] + red[3])) / 4194304.f;
        out_loss[0] = loss;   // dictionary_loss
        out_loss[1] = loss;   // commitment_loss (numerically identical)
    }
}

extern "C" void kernel_launch(void* const* d_in, const int* in_sizes, int n_in,
                              void* d_out, int out_size, void* d_ws, size_t ws_size,
                              hipStream_t stream) {
    const float* x = (const float*)d_in[0];
    const float* E = (const float*)d_in[1];
    float* out      = (float*)d_out;
    float* out_q    = out;             // 4194304
    float* out_loss = out + 4194304;   // 2 scalars
    float* out_idx  = out + 4194306;   // 65536 indices (as float)
    float* esq      = (float*)d_ws;    // 1024 floats
    float* partial  = esq + 1024;      // 1024 floats

    vq_esq_kernel<<<4, 256, 0, stream>>>(E, esq);
    vq_main_kernel<<<1024, 256, 0, stream>>>(x, E, esq, out_q, out_idx, partial);
    vq_loss_kernel<<<1, 256, 0, stream>>>(partial, out_loss);
}

// Round 12
// 117.047 us; speedup vs baseline: 1.3619x; 1.3594x over previous
//
#include <hip/hip_runtime.h>

// VQ: x [B=64, D=64, H=32, W=32] fp32, E [D=64, K=1024] fp32.
// flat rows N = B*H*W = 65536 over (b, h, w) order.
// d_out (float32): [0,4194304) quantized [B,D,H,W]; [4194304] dict_loss;
//   [4194305] commit_loss; [4194306,+65536) indices as floats.
//
// Round-12: no long-lived register state anywhere (R8-R11 lesson: LLVM
// demotes it at any launch-bounds cap, asm pin included). lane = row;
// wave owns a 256-k slice, 8 kt-iters of a 32-k acc tile; per 4-d block the
// thread loads 4 x values from GLOBAL (coalesced b32, 16 KB tile -> L2-hot),
// uses them for 128 FMAs, drops them. E + esq via wave-uniform s_load.
// Inner FMA written as float2 packed fma -> v_pk_fma_f32 if gfx950 has it
// (2x fp32 rate), legalizes to scalar v_fma otherwise. Zero LDS / barriers
// in the main loop.

#define DDIM 64
#define KNUM 1024
#define HWN  1024
#define ROWS_PER_BLOCK 64

typedef __attribute__((ext_vector_type(8))) float float8v;
typedef __attribute__((ext_vector_type(2))) float float2v;

__global__ __launch_bounds__(256) void vq_esq_kernel(const float* __restrict__ E,
                                                     float* __restrict__ esq) {
    int k = blockIdx.x * 256 + threadIdx.x;  // 4 blocks x 256 = 1024
    float s = 0.f;
    #pragma unroll 8
    for (int d = 0; d < DDIM; ++d) {
        float e = E[d * KNUM + k];
        s = fmaf(e, e, s);
    }
    esq[k] = s;
}

__global__ __launch_bounds__(256) void vq_main_kernel(const float* __restrict__ x,
                                                      const float* __restrict__ E,
                                                      const float* __restrict__ esq,
                                                      float* __restrict__ out_q,
                                                      float* __restrict__ out_idx,
                                                      float* __restrict__ partial) {
    __shared__ float bdls[4 * ROWS_PER_BLOCK];  // per-wave row winners (dist)
    __shared__ int   bkls[4 * ROWS_PER_BLOCK];  // per-wave row winners (k)
    __shared__ int   klds[ROWS_PER_BLOCK];
    __shared__ float redlds[4];

    const int t  = threadIdx.x;
    const int wv = t >> 6;        // wave 0..3: owns k-range [wv*256, +256)
    const int ln = t & 63;        // lane = row
    const int n0 = blockIdx.x * ROWS_PER_BLOCK;
    const int b   = n0 >> 10;
    const int hw0 = n0 & 1023;

    // x addresses: row's d-column, stride HWN; loads are coalesced across lanes.
    const float* xcol = x + (size_t)b * (DDIM * HWN) + hw0 + ln;

    const int wvu = __builtin_amdgcn_readfirstlane(wv);  // wave-uniform

    float best  = 3.4e38f;
    int   bestk = 0;

    // 8 kt-iters; wave wv covers k = wvu*256 + kt*32 .. +31 each iter.
    for (int kt = 0; kt < 8; ++kt) {
        const int kbase = wvu * 256 + kt * 32;
        const float* ep = E + kbase;

        float2v s2[16];               // 32 k-accumulators as 16 packed pairs
        #pragma unroll
        for (int i = 0; i < 16; ++i) s2[i] = (float2v){0.f, 0.f};

        #pragma unroll 2
        for (int d4 = 0; d4 < 16; ++d4) {
            // 4 x values: coalesced global b32, L2-hot after first kt.
            float xv0 = xcol[(d4 * 4 + 0) * HWN];
            float xv1 = xcol[(d4 * 4 + 1) * HWN];
            float xv2 = xcol[(d4 * 4 + 2) * HWN];
            float xv3 = xcol[(d4 * 4 + 3) * HWN];
            float xs[4] = {xv0, xv1, xv2, xv3};
            #pragma unroll
            for (int j = 0; j < 4; ++j) {
                const float* erow = ep + (d4 * 4 + j) * KNUM;   // uniform -> s_load
                float8v e0 = *reinterpret_cast<const float8v*>(erow);
                float8v e1 = *reinterpret_cast<const float8v*>(erow + 8);
                float8v e2 = *reinterpret_cast<const float8v*>(erow + 16);
                float8v e3 = *reinterpret_cast<const float8v*>(erow + 24);
                float2v xp = (float2v){xs[j], xs[j]};
                const float2v* e2v0 = reinterpret_cast<const float2v*>(&e0);
                const float2v* e2v1 = reinterpret_cast<const float2v*>(&e1);
                const float2v* e2v2 = reinterpret_cast<const float2v*>(&e2);
                const float2v* e2v3 = reinterpret_cast<const float2v*>(&e3);
                #pragma unroll
                for (int i = 0; i < 4; ++i) {
                    s2[i]      = __builtin_elementwise_fma(xp, e2v0[i], s2[i]);
                    s2[i + 4]  = __builtin_elementwise_fma(xp, e2v1[i], s2[i + 4]);
                    s2[i + 8]  = __builtin_elementwise_fma(xp, e2v2[i], s2[i + 8]);
                    s2[i + 12] = __builtin_elementwise_fma(xp, e2v3[i], s2[i + 12]);
                }
            }
        }

        float8v q0 = *reinterpret_cast<const float8v*>(esq + kbase);
        float8v q1 = *reinterpret_cast<const float8v*>(esq + kbase + 8);
        float8v q2 = *reinterpret_cast<const float8v*>(esq + kbase + 16);
        float8v q3 = *reinterpret_cast<const float8v*>(esq + kbase + 24);
        const float* sflat = reinterpret_cast<const float*>(s2);
        #pragma unroll
        for (int m = 0; m < 32; ++m) {
            float eqv  = (m < 8) ? q0[m & 7] : (m < 16) ? q1[m & 7]
                       : (m < 24) ? q2[m & 7] : q3[m & 7];
            float dist = fmaf(-2.f, sflat[m], eqv);  // |e|^2 - 2 x.e
            int   k    = kbase + m;
            if (dist < best) { best = dist; bestk = k; }  // kt,m ascending -> first-min
        }
    }

    bdls[wv * 64 + ln] = best;
    bkls[wv * 64 + ln] = bestk;
    __syncthreads();

    // cross-wave merge: thread t<64 owns row t (lexicographic (dist, k) min)
    if (t < ROWS_PER_BLOCK) {
        float bd = bdls[t]; int bk = bkls[t];
        #pragma unroll
        for (int w = 1; w < 4; ++w) {
            float od = bdls[w * 64 + t]; int ok = bkls[w * 64 + t];
            if (od < bd || (od == bd && ok < bk)) { bd = od; bk = ok; }
        }
        klds[t] = bk;
        out_idx[n0 + t] = (float)bk;
    }
    __syncthreads();

    // epilogue: wave-uniform guard picks this wave's 16 d's; x re-read from
    // global (L2-hot), E column gather, coalesced store, loss partial.
    const int kwin = klds[ln];
    float lsum = 0.f;
    float* outbase = out_q + (size_t)b * (DDIM * HWN) + hw0 + ln;
    #pragma unroll
    for (int d = 0; d < DDIM; ++d) {
        if ((d >> 4) == wv) {                  // wave-uniform branch
            float q    = E[d * KNUM + kwin];   // L2-resident gather
            float diff = xcol[d * HWN] - q;
            lsum = fmaf(diff, diff, lsum);
            outbase[d * HWN] = q;              // coalesced along hw
        }
    }

    #pragma unroll
    for (int off = 32; off >= 1; off >>= 1)
        lsum += __shfl_xor(lsum, off);
    if ((t & 63) == 0) redlds[t >> 6] = lsum;
    __syncthreads();
    if (t == 0)
        partial[blockIdx.x] = (redlds[0] + redlds[1]) + (redlds[2] + redlds[3]);
}

__global__ __launch_bounds__(256) void vq_loss_kernel(const float* __restrict__ partial,
                                                      float* __restrict__ out_loss) {
    __shared__ float red[4];
    int t = threadIdx.x;
    float s = 0.f;
    #pragma unroll
    for (int it = 0; it < 4; ++it) s += partial[it * 256 + t];
    #pragma unroll
    for (int off = 32; off >= 1; off >>= 1) s += __shfl_xor(s, off);
    if ((t & 63) == 0) red[t >> 6] = s;
    __syncthreads();
    if (t == 0) {
        float loss = ((red[0] + red[1]) + (red[2] + red[3])) / 4194304.f;
        out_loss[0] = loss;   // dictionary_loss
        out_loss[1] = loss;   // commitment_loss (numerically identical)
    }
}

extern "C" void kernel_launch(void* const* d_in, const int* in_sizes, int n_in,
                              void* d_out, int out_size, void* d_ws, size_t ws_size,
                              hipStream_t stream) {
    const float* x = (const float*)d_in[0];
    const float* E = (const float*)d_in[1];
    float* out      = (float*)d_out;
    float* out_q    = out;             // 4194304
    float* out_loss = out + 4194304;   // 2 scalars
    float* out_idx  = out + 4194306;   // 65536 indices (as float)
    float* esq      = (float*)d_ws;    // 1024 floats
    float* partial  = esq + 1024;      // 1024 floats

    vq_esq_kernel<<<4, 256, 0, stream>>>(E, esq);
    vq_main_kernel<<<1024, 256, 0, stream>>>(x, E, esq, out_q, out_idx, partial);
    vq_loss_kernel<<<1, 256, 0, stream>>>(partial, out_loss);
}